// Round 5
// baseline (187.546 us; speedup 1.0000x reference)
//
#include <hip/hip_runtime.h>

// ECConv: out = relu(concat(nf[:8192], mean_seg(relu(EF@We+be).reshape(E,64,64) @ h_src)) @ Wn + bn)
// Sizes: E=65536, N_SRC=32768, N_DST=8192, EDGE_IN=32, NODE_IN=64, HIDDEN=64
// R5: parallel scan (was ~20us serial), edge kernel split into 2 d0-half dispatches
//     (grid 2048, 8 blocks/CU, launch_bounds(256,8)) with chunk1 read-add-write on m,
//     final gather unrolled x2. Lessons: R2 fp32 device atomics are memory-side (~50-85G/s
//     floor); R4 single-block serial scan = 20us; edge grid must exceed 4 blocks/CU for TLP.

typedef float f32x4 __attribute__((ext_vector_type(4)));
typedef __bf16 bf16x8 __attribute__((ext_vector_type(8)));
typedef __bf16 bf16x4 __attribute__((ext_vector_type(4)));

#define E_TOT   65536
#define NDST    8192
#define EPW     72    // bf16 hs pad (fallback kernel)
#define EPF     68    // f32 hs pad (fast kernel), 32 rows

// ================= fast path =================

// ---- prep: blocks 0..63 pack We->(Wp,bp); blocks 64..319 histogram dst ----
// Tile T = d0*4 + ht covers GEMM cols n = (ht*16 + c)*64 + d0, c=0..15.
// B frag for mfma_f32_16x16x32_bf16: lane l holds B[k=(l>>4)*8+j][col=l&15], j=0..7.
__global__ __launch_bounds__(256) void prep_kernel(
    const float* __restrict__ We, const float* __restrict__ be,
    const int* __restrict__ dst, __bf16* __restrict__ Wp, float* __restrict__ bp,
    int* __restrict__ cnt_i) {
  const int b = blockIdx.x;
  if (b < 64) {
    int tid = b * 256 + threadIdx.x;       // 16384 packers
    int T = tid >> 6, l = tid & 63;
    int d0 = T >> 2, ht = T & 3;
    int c = l & 15, kg = l >> 4;
    int ncol = (ht * 16 + c) * 64 + d0;
    bf16x8 v;
#pragma unroll
    for (int j = 0; j < 8; ++j) v[j] = (__bf16)We[(kg * 8 + j) * 4096 + ncol];
    *reinterpret_cast<bf16x8*>(Wp + tid * 8) = v;
    if (l < 16) bp[T * 16 + l] = be[(ht * 16 + l) * 64 + d0];
  } else {
    int e = (b - 64) * 256 + threadIdx.x;
    atomicAdd(&cnt_i[dst[e]], 1);
  }
}

// ---- parallel exclusive scan over 8192 bins (one block, shfl + LDS) ----
__global__ __launch_bounds__(256) void scan_kernel(const int* __restrict__ cnt_i,
                                                   int* __restrict__ off,
                                                   int* __restrict__ cursor) {
  __shared__ int wsum[4];
  const int t = threadIdx.x;           // each thread owns 32 consecutive bins
  const int lane = t & 63, w = t >> 6;
  int vals[32];
  const int4* cp = (const int4*)(cnt_i + t * 32);
#pragma unroll
  for (int i = 0; i < 8; ++i) {
    int4 v = cp[i];
    vals[i * 4 + 0] = v.x; vals[i * 4 + 1] = v.y;
    vals[i * 4 + 2] = v.z; vals[i * 4 + 3] = v.w;
  }
  int loc[32];
  int s = 0;
#pragma unroll
  for (int i = 0; i < 32; ++i) { loc[i] = s; s += vals[i]; }
  // inclusive scan of per-thread totals across the 64-lane wave
  int inc = s;
#pragma unroll
  for (int d = 1; d < 64; d <<= 1) {
    int n = __shfl_up(inc, d, 64);
    if (lane >= d) inc += n;
  }
  if (lane == 63) wsum[w] = inc;
  __syncthreads();
  int base = inc - s;                  // exclusive within wave
#pragma unroll
  for (int i = 0; i < 4; ++i)
    if (i < w) base += wsum[i];        // cross-wave offset
#pragma unroll
  for (int i = 0; i < 32; ++i) {
    int v = base + loc[i];
    off[t * 32 + i] = v;
    cursor[t * 32 + i] = v;
  }
  if (t == 255) off[8192] = E_TOT;
}

// ---- fill: scatter edge ids into CSR order (int atomics on cursor) ----
__global__ void fill_kernel(const int* __restrict__ dst, int* __restrict__ cursor,
                            int* __restrict__ eid) {
  int e = blockIdx.x * 256 + threadIdx.x;
  int slot = atomicAdd(&cursor[dst[e]], 1);
  eid[slot] = e;
}

// ---- edge compute, d0-half CHUNK: m[e][h] (+)= sum_{d in half} relu(ef@We+be)*h_src ----
// Block: 4 waves, 64 edges; wave w owns h-quadrant ht=w. Grid 2048 -> 8 blocks/CU.
template<int CHUNK, bool ADD>
__global__ __launch_bounds__(256, 8) void edge3_kernel(
    const float* __restrict__ nf, const float* __restrict__ ef,
    const int* __restrict__ src, const __bf16* __restrict__ Wp,
    const float* __restrict__ bp, float* __restrict__ m) {
  __shared__ float hs[32 * EPF];   // transposed f32 h_src half: hs[dl][e_local], 8.7 KB
  const int t = threadIdx.x;
  const int eblk = blockIdx.x << 6;

  {
    const int el = t & 63, q = t >> 6;     // 8 d-values per thread
    const int srow = src[eblk + el];
    const f32x4* nfr = (const f32x4*)(nf + (srow << 6) + CHUNK * 32 + (q << 3));
#pragma unroll
    for (int i = 0; i < 2; ++i) {
      f32x4 v = nfr[i];
      const int dbase = (q << 3) + i * 4;
      hs[(dbase + 0) * EPF + el] = v[0];
      hs[(dbase + 1) * EPF + el] = v[1];
      hs[(dbase + 2) * EPF + el] = v[2];
      hs[(dbase + 3) * EPF + el] = v[3];
    }
  }

  const int w = t >> 6, l = t & 63;
  const int c = l & 15, g = l >> 4;

  // A fragments: lane holds A[row=c][k=g*8+j] for 4 row-groups of 16 edges
  bf16x8 afr[4];
#pragma unroll
  for (int as = 0; as < 4; ++as) {
    const int e = eblk + as * 16 + c;
    const f32x4* p = (const f32x4*)(ef + (e << 5) + (g << 3));
    f32x4 v0 = p[0], v1 = p[1];
    bf16x8 a;
    a[0] = (__bf16)v0[0]; a[1] = (__bf16)v0[1]; a[2] = (__bf16)v0[2]; a[3] = (__bf16)v0[3];
    a[4] = (__bf16)v1[0]; a[5] = (__bf16)v1[1]; a[6] = (__bf16)v1[2]; a[7] = (__bf16)v1[3];
    afr[as] = a;
  }

  const int hbase = (w << 4) + c;
  f32x4 acc[4];
  if (ADD) {
#pragma unroll
    for (int as = 0; as < 4; ++as)
#pragma unroll
      for (int r = 0; r < 4; ++r)
        acc[as][r] = m[((eblk + as * 16 + (g << 2) + r) << 6) + hbase];
  } else {
#pragma unroll
    for (int i = 0; i < 4; ++i) { acc[i][0] = 0.f; acc[i][1] = 0.f; acc[i][2] = 0.f; acc[i][3] = 0.f; }
  }

  __syncthreads();

  const bf16x8* WpV = (const bf16x8*)Wp;
  const f32x4 zero = {0.f, 0.f, 0.f, 0.f};

  // depth-2 software pipeline on B-frag + bias (named regs, no runtime-indexed arrays)
  bf16x8 bfrA = WpV[((CHUNK * 32 + 0) * 4 + w) * 64 + l];
  float  bvA  = bp[((CHUNK * 32 + 0) * 4 + w) * 16 + c];
  bf16x8 bfrB = WpV[((CHUNK * 32 + 1) * 4 + w) * 64 + l];
  float  bvB  = bp[((CHUNK * 32 + 1) * 4 + w) * 16 + c];

  for (int dl = 0; dl < 32; dl += 2) {
    {
      const bf16x8 bcur = bfrA;
      const f32x4 cb = {bvA, bvA, bvA, bvA};
      if (dl + 2 < 32) {
        bfrA = WpV[((CHUNK * 32 + dl + 2) * 4 + w) * 64 + l];
        bvA  = bp[((CHUNK * 32 + dl + 2) * 4 + w) * 16 + c];
      }
#pragma unroll
      for (int as = 0; as < 4; ++as) {
        const f32x4 hvf = *(const f32x4*)&hs[dl * EPF + as * 16 + (g << 2)];
        f32x4 tmp = __builtin_amdgcn_mfma_f32_16x16x32_bf16(afr[as], bcur, cb, 0, 0, 0);
        tmp = __builtin_elementwise_max(tmp, zero);
        acc[as] = tmp * hvf + acc[as];
      }
    }
    {
      const bf16x8 bcur = bfrB;
      const f32x4 cb = {bvB, bvB, bvB, bvB};
      if (dl + 3 < 32) {
        bfrB = WpV[((CHUNK * 32 + dl + 3) * 4 + w) * 64 + l];
        bvB  = bp[((CHUNK * 32 + dl + 3) * 4 + w) * 16 + c];
      }
#pragma unroll
      for (int as = 0; as < 4; ++as) {
        const f32x4 hvf = *(const f32x4*)&hs[(dl + 1) * EPF + as * 16 + (g << 2)];
        f32x4 tmp = __builtin_amdgcn_mfma_f32_16x16x32_bf16(afr[as], bcur, cb, 0, 0, 0);
        tmp = __builtin_elementwise_max(tmp, zero);
        acc[as] = tmp * hvf + acc[as];
      }
    }
  }

  // plain coalesced stores: per instr 4 rows x 16 consecutive floats = 4x64B segments
#pragma unroll
  for (int as = 0; as < 4; ++as)
#pragma unroll
    for (int r = 0; r < 4; ++r) {
      const int e = eblk + as * 16 + (g << 2) + r;
      m[(e << 6) + hbase] = acc[as][r];
    }
}

// ---- final: gather-mean per dst (CSR) fused with out = relu(concat@Wn + bn) ----
// Block: 4 waves x 4 rows each = 16 rows. Wn in LDS (32 KB); gather unrolled x2.
__global__ __launch_bounds__(256) void final3_kernel(
    const float* __restrict__ nf, const float* __restrict__ m,
    const int* __restrict__ off, const int* __restrict__ eid,
    const float* __restrict__ Wn, const float* __restrict__ bn,
    float* __restrict__ out) {
  __shared__ float wn_s[128 * 64];   // 32 KB
  __shared__ float hn_s[16 * 64];    // 4 KB
  const int t = threadIdx.x;
#pragma unroll
  for (int i = 0; i < 8; ++i)
    ((f32x4*)wn_s)[i * 256 + t] = ((const f32x4*)Wn)[i * 256 + t];

  const int w = t >> 6, h = t & 63;
  const int row0 = blockIdx.x * 16 + w * 4;

  // gather-mean: wave-uniform eid -> coalesced 256B row reads of m; 2 independent chains
#pragma unroll
  for (int i = 0; i < 4; ++i) {
    const int d = row0 + i;
    const int lo = off[d], hi = off[d + 1];
    float a0 = 0.f, a1 = 0.f;
    int j = lo;
    for (; j + 2 <= hi; j += 2) {
      const int e0 = eid[j], e1 = eid[j + 1];
      a0 += m[(e0 << 6) + h];
      a1 += m[(e1 << 6) + h];
    }
    if (j < hi) a0 += m[(eid[j] << 6) + h];
    const float a = a0 + a1;
    hn_s[(w * 4 + i) * 64 + h] = (hi > lo) ? a * (1.f / (float)(hi - lo)) : 0.f;
  }
  __syncthreads();

  const float bv = bn[h];
  float acc[4] = {bv, bv, bv, bv};
#pragma unroll 4
  for (int k = 0; k < 64; ++k) {
    const float wv = wn_s[k * 64 + h];
#pragma unroll
    for (int i = 0; i < 4; ++i)
      acc[i] = fmaf(nf[(row0 + i) * 64 + k], wv, acc[i]);
  }
#pragma unroll 4
  for (int k = 0; k < 64; ++k) {
    const float wv = wn_s[(64 + k) * 64 + h];
#pragma unroll
    for (int i = 0; i < 4; ++i)
      acc[i] = fmaf(hn_s[(w * 4 + i) * 64 + k], wv, acc[i]);
  }
#pragma unroll
  for (int i = 0; i < 4; ++i)
    out[(row0 + i) * 64 + h] = fmaxf(acc[i], 0.f);
}

// ================= fallback path (R3, proven) =================

__global__ void pack_kernel(const float* __restrict__ We, const float* __restrict__ be,
                            __bf16* __restrict__ Wp, float* __restrict__ bp) {
  int tid = blockIdx.x * 256 + threadIdx.x;
  int T = tid >> 6, l = tid & 63;
  int d0 = T >> 2, ht = T & 3;
  int c = l & 15, kg = l >> 4;
  int ncol = (ht * 16 + c) * 64 + d0;
  bf16x8 v;
#pragma unroll
  for (int j = 0; j < 8; ++j) v[j] = (__bf16)We[(kg * 8 + j) * 4096 + ncol];
  *reinterpret_cast<bf16x8*>(Wp + tid * 8) = v;
  if (l < 16) bp[T * 16 + l] = be[(ht * 16 + l) * 64 + d0];
}

__global__ __launch_bounds__(256, 4) void edge_kernel(
    const float* __restrict__ nf, const float* __restrict__ ef,
    const int* __restrict__ src, const int* __restrict__ dst,
    const __bf16* __restrict__ Wp, const float* __restrict__ bp,
    float* __restrict__ msum, float* __restrict__ cnt_g) {
  __shared__ __bf16 hs[64 * EPW];
  const int t = threadIdx.x;
  const int eblk = blockIdx.x << 6;
  {
    const int el = t & 63, q = t >> 6;
    const int srow = src[eblk + el];
    const f32x4* nfr = (const f32x4*)(nf + (srow << 6) + (q << 4));
#pragma unroll
    for (int i = 0; i < 4; ++i) {
      f32x4 v = nfr[i];
      const int dbase = (q << 4) + i * 4;
      hs[(dbase + 0) * EPW + el] = (__bf16)v[0];
      hs[(dbase + 1) * EPW + el] = (__bf16)v[1];
      hs[(dbase + 2) * EPW + el] = (__bf16)v[2];
      hs[(dbase + 3) * EPW + el] = (__bf16)v[3];
    }
  }
  const int w = t >> 6, l = t & 63, c = l & 15, g = l >> 4;
  bf16x8 afr[4];
#pragma unroll
  for (int as = 0; as < 4; ++as) {
    const int e = eblk + as * 16 + c;
    const f32x4* p = (const f32x4*)(ef + (e << 5) + (g << 3));
    f32x4 v0 = p[0], v1 = p[1];
    bf16x8 a;
    a[0] = (__bf16)v0[0]; a[1] = (__bf16)v0[1]; a[2] = (__bf16)v0[2]; a[3] = (__bf16)v0[3];
    a[4] = (__bf16)v1[0]; a[5] = (__bf16)v1[1]; a[6] = (__bf16)v1[2]; a[7] = (__bf16)v1[3];
    afr[as] = a;
  }
  __syncthreads();
  f32x4 acc[4];
#pragma unroll
  for (int i = 0; i < 4; ++i) { acc[i][0]=0.f; acc[i][1]=0.f; acc[i][2]=0.f; acc[i][3]=0.f; }
  const bf16x8* WpV = (const bf16x8*)Wp;
  const f32x4 zero = {0.f, 0.f, 0.f, 0.f};
#pragma unroll 4
  for (int d0 = 0; d0 < 64; ++d0) {
    const int T = d0 * 4 + w;
    const bf16x8 bfr = WpV[T * 64 + l];
    const float bv = bp[T * 16 + c];
    const f32x4 cb = {bv, bv, bv, bv};
#pragma unroll
    for (int as = 0; as < 4; ++as) {
      const bf16x4 hv = *(const bf16x4*)&hs[d0 * EPW + as * 16 + (g << 2)];
      const f32x4 hvf = {(float)hv[0], (float)hv[1], (float)hv[2], (float)hv[3]};
      f32x4 tmp = __builtin_amdgcn_mfma_f32_16x16x32_bf16(afr[as], bfr, cb, 0, 0, 0);
      tmp = __builtin_elementwise_max(tmp, zero);
      acc[as] = tmp * hvf + acc[as];
    }
  }
#pragma unroll
  for (int as = 0; as < 4; ++as)
#pragma unroll
    for (int r = 0; r < 4; ++r) {
      const int e = eblk + as * 16 + (g << 2) + r;
      const int dd = dst[e];
      unsafeAtomicAdd(msum + (dd << 6) + (w << 4) + c, acc[as][r]);
      if (w == 0 && c == 0) unsafeAtomicAdd(cnt_g + dd, 1.0f);
    }
}

__global__ __launch_bounds__(256) void final_kernel(
    const float* __restrict__ nf, const float* __restrict__ msum,
    const float* __restrict__ cnt, const float* __restrict__ Wn,
    const float* __restrict__ bn, float* __restrict__ out) {
  __shared__ float wn_s[128 * 64];
  const int t = threadIdx.x;
#pragma unroll
  for (int i = 0; i < 8; ++i)
    ((f32x4*)wn_s)[i * 256 + t] = ((const f32x4*)Wn)[i * 256 + t];
  __syncthreads();
  const int w = t >> 6, h = t & 63;
  const int row0 = blockIdx.x * 16 + w * 4;
  const float bv = bn[h];
  float acc[4] = {bv, bv, bv, bv};
  float s[4];
#pragma unroll
  for (int i = 0; i < 4; ++i) {
    const float cv = cnt[row0 + i];
    s[i] = cv > 0.f ? 1.f / cv : 0.f;
  }
#pragma unroll 4
  for (int k = 0; k < 64; ++k) {
    const float wv = wn_s[k * 64 + h];
#pragma unroll
    for (int i = 0; i < 4; ++i) acc[i] = fmaf(nf[(row0 + i) * 64 + k], wv, acc[i]);
  }
#pragma unroll 4
  for (int k = 0; k < 64; ++k) {
    const float wv = wn_s[(64 + k) * 64 + h];
#pragma unroll
    for (int i = 0; i < 4; ++i) acc[i] = fmaf(msum[(row0 + i) * 64 + k] * s[i], wv, acc[i]);
  }
#pragma unroll
  for (int i = 0; i < 4; ++i) out[(row0 + i) * 64 + h] = fmaxf(acc[i], 0.f);
}

// ================= launcher =================

extern "C" void kernel_launch(void* const* d_in, const int* in_sizes, int n_in,
                              void* d_out, int out_size, void* d_ws, size_t ws_size,
                              hipStream_t stream) {
  const float* nf  = (const float*)d_in[0];
  const float* ef  = (const float*)d_in[1];
  const int*   src = (const int*)d_in[2];
  const int*   dst = (const int*)d_in[3];
  const float* We  = (const float*)d_in[4];
  const float* be  = (const float*)d_in[5];
  const float* Wn  = (const float*)d_in[6];
  const float* bn  = (const float*)d_in[7];
  float* out = (float*)d_out;
  char* ws = (char*)d_ws;

  // fast-path layout
  const size_t OFF_M      = 0;                       // 16777216 B  (m: E*64 f32)
  const size_t OFF_OFF    = 16777216;                // 36864 B    (off: 8193 int, padded)
  const size_t OFF_CURSOR = OFF_OFF + 36864;         // 32768 B
  const size_t OFF_CNTI   = OFF_CURSOR + 32768;      // 32768 B
  const size_t OFF_EID    = OFF_CNTI + 32768;        // 262144 B
  const size_t OFF_WP     = OFF_EID + 262144;        // 262144 B
  const size_t OFF_BP     = OFF_WP + 262144;         // 16384 B
  const size_t NEED_FAST  = OFF_BP + 16384;          // ~17.42 MB

  if (ws_size >= NEED_FAST) {
    float*  m      = (float*)(ws + OFF_M);
    int*    off    = (int*)(ws + OFF_OFF);
    int*    cursor = (int*)(ws + OFF_CURSOR);
    int*    cnt_i  = (int*)(ws + OFF_CNTI);
    int*    eid    = (int*)(ws + OFF_EID);
    __bf16* Wp     = (__bf16*)(ws + OFF_WP);
    float*  bp     = (float*)(ws + OFF_BP);

    hipMemsetAsync(cnt_i, 0, 32768, stream);
    prep_kernel<<<320, 256, 0, stream>>>(We, be, dst, Wp, bp, cnt_i);
    scan_kernel<<<1, 256, 0, stream>>>(cnt_i, off, cursor);
    fill_kernel<<<E_TOT / 256, 256, 0, stream>>>(dst, cursor, eid);
    edge3_kernel<0, false><<<E_TOT / 64, 256, 0, stream>>>(nf, ef, src, Wp, bp, m);
    edge3_kernel<1, true ><<<E_TOT / 64, 256, 0, stream>>>(nf, ef, src, Wp, bp, m);
    final3_kernel<<<NDST / 16, 256, 0, stream>>>(nf, m, off, eid, Wn, bn, out);
  } else {
    // R3 fallback (atomic path)
    float* msum = (float*)ws;
    float* cnt  = (float*)(ws + 2097152);
    const size_t need = 2097152 + 32768 + 262144 + 16384;
    __bf16* Wp;
    float*  bp;
    if (ws_size >= need) {
      Wp = (__bf16*)(ws + 2097152 + 32768);
      bp = (float*)(ws + 2097152 + 32768 + 262144);
    } else {
      Wp = (__bf16*)d_out;
      bp = (float*)((char*)d_out + 262144);
    }
    hipMemsetAsync(msum, 0, 2097152 + 32768, stream);
    pack_kernel<<<64, 256, 0, stream>>>(We, be, Wp, bp);
    edge_kernel<<<E_TOT / 64, 256, 0, stream>>>(nf, ef, src, dst, Wp, bp, msum, cnt);
    final_kernel<<<NDST / 16, 256, 0, stream>>>(nf, msum, cnt, Wn, bn, out);
  }
}

// Round 6
// 82.759 us; speedup vs baseline: 2.2662x; 2.2662x over previous
//
#include <hip/hip_runtime.h>

// ECConv: out = relu(concat(nf[:8192], mean_seg(relu(EF@We+be).reshape(E,64,64) @ h_src)) @ Wn + bn)
// Sizes: E=65536, N_SRC=32768, N_DST=8192, EDGE_IN=32, NODE_IN=64, HIDDEN=64
// R6: concurrent d0-half split in ONE dispatch (grid 2048 -> 8 blocks/CU), halves write
//     disjoint m0/m1 (no atomics, no RMW); final sums both. launch_bounds kept at (256,4).
// Lessons: R2 fp32 device atomics are memory-side (~50-85G dword/s floor). R4 serial scan
//     = 20us. R5 launch_bounds(256,8) -> VGPR 32 -> spill -> 92MB scratch writes; sequential
//     dispatches do NOT increase blocks/CU (concurrency needs one grid).

typedef float f32x4 __attribute__((ext_vector_type(4)));
typedef __bf16 bf16x8 __attribute__((ext_vector_type(8)));
typedef __bf16 bf16x4 __attribute__((ext_vector_type(4)));

#define E_TOT   65536
#define NDST    8192
#define EPW     72    // bf16 hs pad (atomic-fallback kernel)
#define EPF     68    // f32 hs pad

// ---- prep: blocks 0..63 pack We->(Wp,bp); blocks 64..319 histogram dst ----
// Tile T = d0*4 + ht covers GEMM cols n = (ht*16 + c)*64 + d0, c=0..15.
// B frag for mfma_f32_16x16x32_bf16: lane l holds B[k=(l>>4)*8+j][col=l&15], j=0..7.
__global__ __launch_bounds__(256) void prep_kernel(
    const float* __restrict__ We, const float* __restrict__ be,
    const int* __restrict__ dst, __bf16* __restrict__ Wp, float* __restrict__ bp,
    int* __restrict__ cnt_i) {
  const int b = blockIdx.x;
  if (b < 64) {
    int tid = b * 256 + threadIdx.x;
    int T = tid >> 6, l = tid & 63;
    int d0 = T >> 2, ht = T & 3;
    int c = l & 15, kg = l >> 4;
    int ncol = (ht * 16 + c) * 64 + d0;
    bf16x8 v;
#pragma unroll
    for (int j = 0; j < 8; ++j) v[j] = (__bf16)We[(kg * 8 + j) * 4096 + ncol];
    *reinterpret_cast<bf16x8*>(Wp + tid * 8) = v;
    if (l < 16) bp[T * 16 + l] = be[(ht * 16 + l) * 64 + d0];
  } else {
    int e = (b - 64) * 256 + threadIdx.x;
    atomicAdd(&cnt_i[dst[e]], 1);
  }
}

// ---- parallel exclusive scan over 8192 bins (one block, shfl + LDS) ----
__global__ __launch_bounds__(256) void scan_kernel(const int* __restrict__ cnt_i,
                                                   int* __restrict__ off,
                                                   int* __restrict__ cursor) {
  __shared__ int wsum[4];
  const int t = threadIdx.x;           // each thread owns 32 consecutive bins
  const int lane = t & 63, w = t >> 6;
  int vals[32];
  const int4* cp = (const int4*)(cnt_i + t * 32);
#pragma unroll
  for (int i = 0; i < 8; ++i) {
    int4 v = cp[i];
    vals[i * 4 + 0] = v.x; vals[i * 4 + 1] = v.y;
    vals[i * 4 + 2] = v.z; vals[i * 4 + 3] = v.w;
  }
  int loc[32];
  int s = 0;
#pragma unroll
  for (int i = 0; i < 32; ++i) { loc[i] = s; s += vals[i]; }
  int inc = s;
#pragma unroll
  for (int d = 1; d < 64; d <<= 1) {
    int n = __shfl_up(inc, d, 64);
    if (lane >= d) inc += n;
  }
  if (lane == 63) wsum[w] = inc;
  __syncthreads();
  int base = inc - s;
#pragma unroll
  for (int i = 0; i < 4; ++i)
    if (i < w) base += wsum[i];
#pragma unroll
  for (int i = 0; i < 32; ++i) {
    int v = base + loc[i];
    off[t * 32 + i] = v;
    cursor[t * 32 + i] = v;
  }
  if (t == 255) off[8192] = E_TOT;
}

// ---- fill: scatter edge ids into CSR order (int atomics on cursor) ----
__global__ void fill_kernel(const int* __restrict__ dst, int* __restrict__ cursor,
                            int* __restrict__ eid) {
  int e = blockIdx.x * 256 + threadIdx.x;
  int slot = atomicAdd(&cursor[dst[e]], 1);
  eid[slot] = e;
}

// ---- edge compute over DN d0-columns starting at runtime d0base ----
// SPLIT: grid 2048; bid>=1024 -> half 1 (d0 32..63, writes m1), else half 0 (m0).
//        Pair blocks eb / eb+1024 land on the same XCD (1024 % 8 == 0) -> ef/Wp L2-share.
// FULL:  grid 1024, DN=64, all into m0.
template<int DN>
__global__ __launch_bounds__(256, 4) void edge4_kernel(
    const float* __restrict__ nf, const float* __restrict__ ef,
    const int* __restrict__ src, const __bf16* __restrict__ Wp,
    const float* __restrict__ bp, float* __restrict__ m0, float* __restrict__ m1) {
  __shared__ float hs[DN * EPF];   // transposed f32 h_src: hs[dl][e_local]
  const int t = threadIdx.x;
  const int half = (DN == 64) ? 0 : (blockIdx.x >> 10);
  const int eblk = (DN == 64) ? (blockIdx.x << 6) : ((blockIdx.x & 1023) << 6);
  const int d0base = half << 5;
  float* __restrict__ mo = half ? m1 : m0;

  // stage h_src d0-slice transposed: thread t -> edge el=t&63, d-group q=t>>6 (DN/4 each)
  {
    const int el = t & 63, q = t >> 6;
    const int srow = src[eblk + el];
    const f32x4* nfr = (const f32x4*)(nf + (srow << 6) + d0base + q * (DN / 4));
#pragma unroll
    for (int i = 0; i < DN / 16; ++i) {
      f32x4 v = nfr[i];
      const int dbase = q * (DN / 4) + i * 4;
      hs[(dbase + 0) * EPF + el] = v[0];
      hs[(dbase + 1) * EPF + el] = v[1];
      hs[(dbase + 2) * EPF + el] = v[2];
      hs[(dbase + 3) * EPF + el] = v[3];
    }
  }

  const int w = t >> 6, l = t & 63;
  const int c = l & 15, g = l >> 4;

  // A fragments: lane holds A[row=c][k=g*8+j] for 4 row-groups of 16 edges
  bf16x8 afr[4];
#pragma unroll
  for (int as = 0; as < 4; ++as) {
    const int e = eblk + as * 16 + c;
    const f32x4* p = (const f32x4*)(ef + (e << 5) + (g << 3));
    f32x4 v0 = p[0], v1 = p[1];
    bf16x8 a;
    a[0] = (__bf16)v0[0]; a[1] = (__bf16)v0[1]; a[2] = (__bf16)v0[2]; a[3] = (__bf16)v0[3];
    a[4] = (__bf16)v1[0]; a[5] = (__bf16)v1[1]; a[6] = (__bf16)v1[2]; a[7] = (__bf16)v1[3];
    afr[as] = a;
  }

  __syncthreads();

  f32x4 acc[4];
#pragma unroll
  for (int i = 0; i < 4; ++i) { acc[i][0] = 0.f; acc[i][1] = 0.f; acc[i][2] = 0.f; acc[i][3] = 0.f; }

  const bf16x8* WpV = (const bf16x8*)Wp;
  const f32x4 zero = {0.f, 0.f, 0.f, 0.f};

  // depth-2 software pipeline on B-frag + bias (named regs, rule-#20-safe)
  bf16x8 bfrA = WpV[((d0base + 0) * 4 + w) * 64 + l];
  float  bvA  = bp[((d0base + 0) * 4 + w) * 16 + c];
  bf16x8 bfrB = WpV[((d0base + 1) * 4 + w) * 64 + l];
  float  bvB  = bp[((d0base + 1) * 4 + w) * 16 + c];

  for (int dl = 0; dl < DN; dl += 2) {
    {
      const bf16x8 bcur = bfrA;
      const f32x4 cb = {bvA, bvA, bvA, bvA};
      if (dl + 2 < DN) {
        bfrA = WpV[((d0base + dl + 2) * 4 + w) * 64 + l];
        bvA  = bp[((d0base + dl + 2) * 4 + w) * 16 + c];
      }
#pragma unroll
      for (int as = 0; as < 4; ++as) {
        const f32x4 hvf = *(const f32x4*)&hs[dl * EPF + as * 16 + (g << 2)];
        f32x4 tmp = __builtin_amdgcn_mfma_f32_16x16x32_bf16(afr[as], bcur, cb, 0, 0, 0);
        tmp = __builtin_elementwise_max(tmp, zero);
        acc[as] = tmp * hvf + acc[as];
      }
    }
    {
      const bf16x8 bcur = bfrB;
      const f32x4 cb = {bvB, bvB, bvB, bvB};
      if (dl + 3 < DN) {
        bfrB = WpV[((d0base + dl + 3) * 4 + w) * 64 + l];
        bvB  = bp[((d0base + dl + 3) * 4 + w) * 16 + c];
      }
#pragma unroll
      for (int as = 0; as < 4; ++as) {
        const f32x4 hvf = *(const f32x4*)&hs[(dl + 1) * EPF + as * 16 + (g << 2)];
        f32x4 tmp = __builtin_amdgcn_mfma_f32_16x16x32_bf16(afr[as], bcur, cb, 0, 0, 0);
        tmp = __builtin_elementwise_max(tmp, zero);
        acc[as] = tmp * hvf + acc[as];
      }
    }
  }

  // plain coalesced stores: per instr 4 rows x 16 consecutive floats = 4x64B segments
  const int hbase = (w << 4) + c;
#pragma unroll
  for (int as = 0; as < 4; ++as)
#pragma unroll
    for (int r = 0; r < 4; ++r) {
      const int e = eblk + as * 16 + (g << 2) + r;
      mo[(e << 6) + hbase] = acc[as][r];
    }
}

// ---- final: gather-mean per dst (CSR, summing m0[+m1]) fused with relu(concat@Wn+bn) ----
// Block: 4 waves x 2 rows each = 8 rows; grid 1024. Wn in LDS (32 KB).
template<bool SPLIT>
__global__ __launch_bounds__(256) void final4_kernel(
    const float* __restrict__ nf, const float* __restrict__ m0,
    const float* __restrict__ m1, const int* __restrict__ off,
    const int* __restrict__ eid, const float* __restrict__ Wn,
    const float* __restrict__ bn, float* __restrict__ out) {
  __shared__ float wn_s[128 * 64];   // 32 KB
  __shared__ float hn_s[8 * 64];     // 2 KB
  const int t = threadIdx.x;
#pragma unroll
  for (int i = 0; i < 8; ++i)
    ((f32x4*)wn_s)[i * 256 + t] = ((const f32x4*)Wn)[i * 256 + t];

  const int w = t >> 6, h = t & 63;
  const int row0 = blockIdx.x * 8 + w * 2;

  // gather-mean: wave-uniform eid -> coalesced 256B row reads; 4 independent chains
#pragma unroll
  for (int i = 0; i < 2; ++i) {
    const int d = row0 + i;
    const int lo = off[d], hi = off[d + 1];
    float a0 = 0.f, a1 = 0.f, b0 = 0.f, b1 = 0.f;
    int j = lo;
    for (; j + 2 <= hi; j += 2) {
      const int e0 = eid[j], e1 = eid[j + 1];
      a0 += m0[(e0 << 6) + h];
      a1 += m0[(e1 << 6) + h];
      if (SPLIT) {
        b0 += m1[(e0 << 6) + h];
        b1 += m1[(e1 << 6) + h];
      }
    }
    if (j < hi) {
      const int e0 = eid[j];
      a0 += m0[(e0 << 6) + h];
      if (SPLIT) b0 += m1[(e0 << 6) + h];
    }
    const float a = (a0 + a1) + (b0 + b1);
    hn_s[(w * 2 + i) * 64 + h] = (hi > lo) ? a * (1.f / (float)(hi - lo)) : 0.f;
  }
  __syncthreads();

  const float bv = bn[h];
  float acc[2] = {bv, bv};
#pragma unroll 4
  for (int k = 0; k < 64; ++k) {
    const float wv = wn_s[k * 64 + h];
#pragma unroll
    for (int i = 0; i < 2; ++i)
      acc[i] = fmaf(nf[(row0 + i) * 64 + k], wv, acc[i]);
  }
#pragma unroll 4
  for (int k = 0; k < 64; ++k) {
    const float wv = wn_s[(64 + k) * 64 + h];
#pragma unroll
    for (int i = 0; i < 2; ++i)
      acc[i] = fmaf(hn_s[(w * 2 + i) * 64 + k], wv, acc[i]);
  }
#pragma unroll
  for (int i = 0; i < 2; ++i)
    out[(row0 + i) * 64 + h] = fmaxf(acc[i], 0.f);
}

// ================= atomic fallback (R3, proven) =================

__global__ __launch_bounds__(256, 4) void edge_kernel(
    const float* __restrict__ nf, const float* __restrict__ ef,
    const int* __restrict__ src, const int* __restrict__ dst,
    const __bf16* __restrict__ Wp, const float* __restrict__ bp,
    float* __restrict__ msum, float* __restrict__ cnt_g) {
  __shared__ __bf16 hs[64 * EPW];
  const int t = threadIdx.x;
  const int eblk = blockIdx.x << 6;
  {
    const int el = t & 63, q = t >> 6;
    const int srow = src[eblk + el];
    const f32x4* nfr = (const f32x4*)(nf + (srow << 6) + (q << 4));
#pragma unroll
    for (int i = 0; i < 4; ++i) {
      f32x4 v = nfr[i];
      const int dbase = (q << 4) + i * 4;
      hs[(dbase + 0) * EPW + el] = (__bf16)v[0];
      hs[(dbase + 1) * EPW + el] = (__bf16)v[1];
      hs[(dbase + 2) * EPW + el] = (__bf16)v[2];
      hs[(dbase + 3) * EPW + el] = (__bf16)v[3];
    }
  }
  const int w = t >> 6, l = t & 63, c = l & 15, g = l >> 4;
  bf16x8 afr[4];
#pragma unroll
  for (int as = 0; as < 4; ++as) {
    const int e = eblk + as * 16 + c;
    const f32x4* p = (const f32x4*)(ef + (e << 5) + (g << 3));
    f32x4 v0 = p[0], v1 = p[1];
    bf16x8 a;
    a[0] = (__bf16)v0[0]; a[1] = (__bf16)v0[1]; a[2] = (__bf16)v0[2]; a[3] = (__bf16)v0[3];
    a[4] = (__bf16)v1[0]; a[5] = (__bf16)v1[1]; a[6] = (__bf16)v1[2]; a[7] = (__bf16)v1[3];
    afr[as] = a;
  }
  __syncthreads();
  f32x4 acc[4];
#pragma unroll
  for (int i = 0; i < 4; ++i) { acc[i][0]=0.f; acc[i][1]=0.f; acc[i][2]=0.f; acc[i][3]=0.f; }
  const bf16x8* WpV = (const bf16x8*)Wp;
  const f32x4 zero = {0.f, 0.f, 0.f, 0.f};
#pragma unroll 4
  for (int d0 = 0; d0 < 64; ++d0) {
    const int T = d0 * 4 + w;
    const bf16x8 bfr = WpV[T * 64 + l];
    const float bv = bp[T * 16 + c];
    const f32x4 cb = {bv, bv, bv, bv};
#pragma unroll
    for (int as = 0; as < 4; ++as) {
      const bf16x4 hv = *(const bf16x4*)&hs[d0 * EPW + as * 16 + (g << 2)];
      const f32x4 hvf = {(float)hv[0], (float)hv[1], (float)hv[2], (float)hv[3]};
      f32x4 tmp = __builtin_amdgcn_mfma_f32_16x16x32_bf16(afr[as], bfr, cb, 0, 0, 0);
      tmp = __builtin_elementwise_max(tmp, zero);
      acc[as] = tmp * hvf + acc[as];
    }
  }
#pragma unroll
  for (int as = 0; as < 4; ++as)
#pragma unroll
    for (int r = 0; r < 4; ++r) {
      const int e = eblk + as * 16 + (g << 2) + r;
      const int dd = dst[e];
      unsafeAtomicAdd(msum + (dd << 6) + (w << 4) + c, acc[as][r]);
      if (w == 0 && c == 0) unsafeAtomicAdd(cnt_g + dd, 1.0f);
    }
}

__global__ __launch_bounds__(256) void final_kernel(
    const float* __restrict__ nf, const float* __restrict__ msum,
    const float* __restrict__ cnt, const float* __restrict__ Wn,
    const float* __restrict__ bn, float* __restrict__ out) {
  __shared__ float wn_s[128 * 64];
  const int t = threadIdx.x;
#pragma unroll
  for (int i = 0; i < 8; ++i)
    ((f32x4*)wn_s)[i * 256 + t] = ((const f32x4*)Wn)[i * 256 + t];
  __syncthreads();
  const int w = t >> 6, h = t & 63;
  const int row0 = blockIdx.x * 16 + w * 4;
  const float bv = bn[h];
  float acc[4] = {bv, bv, bv, bv};
  float s[4];
#pragma unroll
  for (int i = 0; i < 4; ++i) {
    const float cv = cnt[row0 + i];
    s[i] = cv > 0.f ? 1.f / cv : 0.f;
  }
#pragma unroll 4
  for (int k = 0; k < 64; ++k) {
    const float wv = wn_s[k * 64 + h];
#pragma unroll
    for (int i = 0; i < 4; ++i) acc[i] = fmaf(nf[(row0 + i) * 64 + k], wv, acc[i]);
  }
#pragma unroll 4
  for (int k = 0; k < 64; ++k) {
    const float wv = wn_s[(64 + k) * 64 + h];
#pragma unroll
    for (int i = 0; i < 4; ++i) acc[i] = fmaf(msum[(row0 + i) * 64 + k] * s[i], wv, acc[i]);
  }
#pragma unroll
  for (int i = 0; i < 4; ++i) out[(row0 + i) * 64 + h] = fmaxf(acc[i], 0.f);
}

// ================= launcher =================

extern "C" void kernel_launch(void* const* d_in, const int* in_sizes, int n_in,
                              void* d_out, int out_size, void* d_ws, size_t ws_size,
                              hipStream_t stream) {
  const float* nf  = (const float*)d_in[0];
  const float* ef  = (const float*)d_in[1];
  const int*   src = (const int*)d_in[2];
  const int*   dst = (const int*)d_in[3];
  const float* We  = (const float*)d_in[4];
  const float* be  = (const float*)d_in[5];
  const float* Wn  = (const float*)d_in[6];
  const float* bn  = (const float*)d_in[7];
  float* out = (float*)d_out;
  char* ws = (char*)d_ws;

  const size_t MB = 16777216;  // m buffer bytes (E*64*4)
  // tier-1 (split): m0, m1, off, cursor, cnt_i, eid, Wp, bp
  const size_t T1_OFF    = 2 * MB;
  const size_t T1_CURSOR = T1_OFF + 36864;
  const size_t T1_CNTI   = T1_CURSOR + 32768;
  const size_t T1_EID    = T1_CNTI + 32768;
  const size_t T1_WP     = T1_EID + 262144;
  const size_t T1_BP     = T1_WP + 262144;
  const size_t NEED1     = T1_BP + 16384;      // ~34.2 MB
  // tier-2 (full): m0 only
  const size_t T2_OFF    = MB;
  const size_t T2_CURSOR = T2_OFF + 36864;
  const size_t T2_CNTI   = T2_CURSOR + 32768;
  const size_t T2_EID    = T2_CNTI + 32768;
  const size_t T2_WP     = T2_EID + 262144;
  const size_t T2_BP     = T2_WP + 262144;
  const size_t NEED2     = T2_BP + 16384;      // ~17.4 MB

  if (ws_size >= NEED1) {
    float*  m0     = (float*)ws;
    float*  m1     = (float*)(ws + MB);
    int*    off    = (int*)(ws + T1_OFF);
    int*    cursor = (int*)(ws + T1_CURSOR);
    int*    cnt_i  = (int*)(ws + T1_CNTI);
    int*    eid    = (int*)(ws + T1_EID);
    __bf16* Wp     = (__bf16*)(ws + T1_WP);
    float*  bp     = (float*)(ws + T1_BP);

    hipMemsetAsync(cnt_i, 0, 32768, stream);
    prep_kernel<<<320, 256, 0, stream>>>(We, be, dst, Wp, bp, cnt_i);
    scan_kernel<<<1, 256, 0, stream>>>(cnt_i, off, cursor);
    fill_kernel<<<E_TOT / 256, 256, 0, stream>>>(dst, cursor, eid);
    edge4_kernel<32><<<2048, 256, 0, stream>>>(nf, ef, src, Wp, bp, m0, m1);
    final4_kernel<true><<<NDST / 8, 256, 0, stream>>>(nf, m0, m1, off, eid, Wn, bn, out);
  } else if (ws_size >= NEED2) {
    float*  m0     = (float*)ws;
    int*    off    = (int*)(ws + T2_OFF);
    int*    cursor = (int*)(ws + T2_CURSOR);
    int*    cnt_i  = (int*)(ws + T2_CNTI);
    int*    eid    = (int*)(ws + T2_EID);
    __bf16* Wp     = (__bf16*)(ws + T2_WP);
    float*  bp     = (float*)(ws + T2_BP);

    hipMemsetAsync(cnt_i, 0, 32768, stream);
    prep_kernel<<<320, 256, 0, stream>>>(We, be, dst, Wp, bp, cnt_i);
    scan_kernel<<<1, 256, 0, stream>>>(cnt_i, off, cursor);
    fill_kernel<<<E_TOT / 256, 256, 0, stream>>>(dst, cursor, eid);
    edge4_kernel<64><<<1024, 256, 0, stream>>>(nf, ef, src, Wp, bp, m0, m0);
    final4_kernel<false><<<NDST / 8, 256, 0, stream>>>(nf, m0, m0, off, eid, Wn, bn, out);
  } else {
    // atomic fallback
    float* msum = (float*)ws;
    float* cnt  = (float*)(ws + 2097152);
    const size_t need = 2097152 + 32768 + 262144 + 16384;
    __bf16* Wp;
    float*  bp;
    if (ws_size >= need) {
      Wp = (__bf16*)(ws + 2097152 + 32768);
      bp = (float*)(ws + 2097152 + 32768 + 262144);
    } else {
      Wp = (__bf16*)d_out;
      bp = (float*)((char*)d_out + 262144);
    }
    hipMemsetAsync(msum, 0, 2097152 + 32768, stream);
    prep_kernel<<<64, 256, 0, stream>>>(We, be, dst, Wp, bp, (int*)cnt);  // pack-only blocks
    edge_kernel<<<E_TOT / 64, 256, 0, stream>>>(nf, ef, src, dst, Wp, bp, msum, cnt);
    final_kernel<<<NDST / 16, 256, 0, stream>>>(nf, msum, cnt, Wn, bn, out);
  }
}

// Round 7
// 79.742 us; speedup vs baseline: 2.3519x; 1.0378x over previous
//
#include <hip/hip_runtime.h>

// ECConv: out = relu(concat(nf[:8192], mean_seg(relu(EF@We+be).reshape(E,64,64) @ h_src)) @ Wn + bn)
// Sizes: E=65536, N_SRC=32768, N_DST=8192, EDGE_IN=32, NODE_IN=64, HIDDEN=64
// R7: VALU-cut round. Model (R4 vs R6): throughput-bound, not latency-bound; one 16x16x32
//     MFMA = ~19 SIMD-cyc (matrix pipe shared per CU) -> MFMA floor 8.3us; measured VALU-busy
//     25us = 2-3x static count -> suspect scalarized epilogue + AGPR acc churn + addressing.
//     Fixes: v_pk_fma_f32 asm epilogue with "+v" (forces arch VGPRs), unroll 8 (imm-folded
//     ds offsets), DN=64 single-m, launch_bounds(256,2) (no forced spill), hist fused in edge.
// Lessons: R2 fp32 device atomics memory-side (~50-85G dword/s). R4 serial scan 20us.
//     R5 launch_bounds-forced VGPR=32 -> 92MB spill traffic; sequential dispatches don't stack.

typedef float f32x4 __attribute__((ext_vector_type(4)));
typedef float f32x2 __attribute__((ext_vector_type(2)));
typedef __bf16 bf16x8 __attribute__((ext_vector_type(8)));
typedef __bf16 bf16x4 __attribute__((ext_vector_type(4)));

#define E_TOT   65536
#define NDST    8192
#define EPW     72    // bf16 hs pad (atomic-fallback kernel)
#define EPF     68    // f32 hs pad

// ---- prep: pack We (fp32 [32][4096]) -> MFMA-B fragment order bf16 + bias tiles ----
// Tile T = d0*4 + ht covers GEMM cols n = (ht*16 + c)*64 + d0, c=0..15.
// B frag for mfma_f32_16x16x32_bf16: lane l holds B[k=(l>>4)*8+j][col=l&15], j=0..7.
__global__ __launch_bounds__(256) void prep_kernel(
    const float* __restrict__ We, const float* __restrict__ be,
    __bf16* __restrict__ Wp, float* __restrict__ bp) {
  int tid = blockIdx.x * 256 + threadIdx.x;       // 16384 packers
  int T = tid >> 6, l = tid & 63;
  int d0 = T >> 2, ht = T & 3;
  int c = l & 15, kg = l >> 4;
  int ncol = (ht * 16 + c) * 64 + d0;
  bf16x8 v;
#pragma unroll
  for (int j = 0; j < 8; ++j) v[j] = (__bf16)We[(kg * 8 + j) * 4096 + ncol];
  *reinterpret_cast<bf16x8*>(Wp + tid * 8) = v;
  if (l < 16) bp[T * 16 + l] = be[(ht * 16 + l) * 64 + d0];
}

// ---- parallel exclusive scan over 8192 bins (one block, shfl + LDS) ----
__global__ __launch_bounds__(256) void scan_kernel(const int* __restrict__ cnt_i,
                                                   int* __restrict__ off,
                                                   int* __restrict__ cursor) {
  __shared__ int wsum[4];
  const int t = threadIdx.x;           // each thread owns 32 consecutive bins
  const int lane = t & 63, w = t >> 6;
  int vals[32];
  const int4* cp = (const int4*)(cnt_i + t * 32);
#pragma unroll
  for (int i = 0; i < 8; ++i) {
    int4 v = cp[i];
    vals[i * 4 + 0] = v.x; vals[i * 4 + 1] = v.y;
    vals[i * 4 + 2] = v.z; vals[i * 4 + 3] = v.w;
  }
  int loc[32];
  int s = 0;
#pragma unroll
  for (int i = 0; i < 32; ++i) { loc[i] = s; s += vals[i]; }
  int inc = s;
#pragma unroll
  for (int d = 1; d < 64; d <<= 1) {
    int n = __shfl_up(inc, d, 64);
    if (lane >= d) inc += n;
  }
  if (lane == 63) wsum[w] = inc;
  __syncthreads();
  int base = inc - s;
#pragma unroll
  for (int i = 0; i < 4; ++i)
    if (i < w) base += wsum[i];
#pragma unroll
  for (int i = 0; i < 32; ++i) {
    int v = base + loc[i];
    off[t * 32 + i] = v;
    cursor[t * 32 + i] = v;
  }
  if (t == 255) off[8192] = E_TOT;
}

// ---- fill: scatter edge ids into CSR order (int atomics on cursor) ----
__global__ void fill_kernel(const int* __restrict__ dst, int* __restrict__ cursor,
                            int* __restrict__ eid) {
  int e = blockIdx.x * 256 + threadIdx.x;
  int slot = atomicAdd(&cursor[dst[e]], 1);
  eid[slot] = e;
}

// ---- edge compute: m[e][h] = sum_d relu(ef[e]@We[:,h,d] + be[h,d]) * h_src[e][d] ----
// Block: 4 waves, 64 edges; wave w owns h-quadrant ht=w; grid 1024. Also does dst histogram.
// acc kept as f32x2 pairs updated via v_pk_fma_f32 asm ("+v" forces arch VGPRs, no AGPR churn).
__global__ __launch_bounds__(256, 2) void edge5_kernel(
    const float* __restrict__ nf, const float* __restrict__ ef,
    const int* __restrict__ src, const int* __restrict__ dst,
    const __bf16* __restrict__ Wp, const float* __restrict__ bp,
    float* __restrict__ m, int* __restrict__ cnt_i) {
  __shared__ float hs[64 * EPF];   // transposed f32 h_src: hs[d][e_local], 17.4 KB
  const int t = threadIdx.x;
  const int eblk = blockIdx.x << 6;

  // stage h_src transposed: thread t -> edge el=t&63, d-quarter q=t>>6 (16 d each)
  {
    const int el = t & 63, q = t >> 6;
    const int srow = src[eblk + el];
    const f32x4* nfr = (const f32x4*)(nf + (srow << 6) + (q << 4));
#pragma unroll
    for (int i = 0; i < 4; ++i) {
      f32x4 v = nfr[i];
      const int dbase = (q << 4) + i * 4;
      hs[(dbase + 0) * EPF + el] = v[0];
      hs[(dbase + 1) * EPF + el] = v[1];
      hs[(dbase + 2) * EPF + el] = v[2];
      hs[(dbase + 3) * EPF + el] = v[3];
    }
  }

  // fused dst histogram (feeds CSR for final; cnt_i pre-zeroed by memset)
  if (t < 64) atomicAdd(&cnt_i[dst[eblk + t]], 1);

  const int w = t >> 6, l = t & 63;
  const int c = l & 15, g = l >> 4;

  // A fragments: lane holds A[row=c][k=g*8+j] for 4 row-groups of 16 edges
  bf16x8 afr[4];
#pragma unroll
  for (int as = 0; as < 4; ++as) {
    const int e = eblk + as * 16 + c;
    const f32x4* p = (const f32x4*)(ef + (e << 5) + (g << 3));
    f32x4 v0 = p[0], v1 = p[1];
    bf16x8 a;
    a[0] = (__bf16)v0[0]; a[1] = (__bf16)v0[1]; a[2] = (__bf16)v0[2]; a[3] = (__bf16)v0[3];
    a[4] = (__bf16)v1[0]; a[5] = (__bf16)v1[1]; a[6] = (__bf16)v1[2]; a[7] = (__bf16)v1[3];
    afr[as] = a;
  }

  __syncthreads();

  f32x2 accA[4], accB[4];   // acc pairs: A = C-rows (g*4+0, g*4+1), B = (g*4+2, g*4+3)
#pragma unroll
  for (int i = 0; i < 4; ++i) {
    accA[i][0] = 0.f; accA[i][1] = 0.f;
    accB[i][0] = 0.f; accB[i][1] = 0.f;
  }

  const bf16x8* WpV = (const bf16x8*)Wp;

  // depth-2 software pipeline on B-frag + bias (named regs, rule-#20-safe)
  bf16x8 bfrA = WpV[(0 * 4 + w) * 64 + l];
  float  bvA  = bp[(0 * 4 + w) * 16 + c];
  bf16x8 bfrB = WpV[(1 * 4 + w) * 64 + l];
  float  bvB  = bp[(1 * 4 + w) * 16 + c];

#pragma unroll 8
  for (int dl = 0; dl < 64; dl += 2) {
    {
      const bf16x8 bcur = bfrA;
      const f32x4 cb = {bvA, bvA, bvA, bvA};
      if (dl + 2 < 64) {
        bfrA = WpV[((dl + 2) * 4 + w) * 64 + l];
        bvA  = bp[((dl + 2) * 4 + w) * 16 + c];
      }
#pragma unroll
      for (int as = 0; as < 4; ++as) {
        const f32x4 hvf = *(const f32x4*)&hs[dl * EPF + as * 16 + (g << 2)];
        f32x4 tmp = __builtin_amdgcn_mfma_f32_16x16x32_bf16(afr[as], bcur, cb, 0, 0, 0);
        f32x2 tl = {fmaxf(tmp[0], 0.f), fmaxf(tmp[1], 0.f)};
        f32x2 th = {fmaxf(tmp[2], 0.f), fmaxf(tmp[3], 0.f)};
        f32x2 hl = __builtin_shufflevector(hvf, hvf, 0, 1);
        f32x2 hh = __builtin_shufflevector(hvf, hvf, 2, 3);
        asm("v_pk_fma_f32 %0, %1, %2, %0" : "+v"(accA[as]) : "v"(tl), "v"(hl));
        asm("v_pk_fma_f32 %0, %1, %2, %0" : "+v"(accB[as]) : "v"(th), "v"(hh));
      }
    }
    {
      const bf16x8 bcur = bfrB;
      const f32x4 cb = {bvB, bvB, bvB, bvB};
      if (dl + 3 < 64) {
        bfrB = WpV[((dl + 3) * 4 + w) * 64 + l];
        bvB  = bp[((dl + 3) * 4 + w) * 16 + c];
      }
#pragma unroll
      for (int as = 0; as < 4; ++as) {
        const f32x4 hvf = *(const f32x4*)&hs[(dl + 1) * EPF + as * 16 + (g << 2)];
        f32x4 tmp = __builtin_amdgcn_mfma_f32_16x16x32_bf16(afr[as], bcur, cb, 0, 0, 0);
        f32x2 tl = {fmaxf(tmp[0], 0.f), fmaxf(tmp[1], 0.f)};
        f32x2 th = {fmaxf(tmp[2], 0.f), fmaxf(tmp[3], 0.f)};
        f32x2 hl = __builtin_shufflevector(hvf, hvf, 0, 1);
        f32x2 hh = __builtin_shufflevector(hvf, hvf, 2, 3);
        asm("v_pk_fma_f32 %0, %1, %2, %0" : "+v"(accA[as]) : "v"(tl), "v"(hl));
        asm("v_pk_fma_f32 %0, %1, %2, %0" : "+v"(accB[as]) : "v"(th), "v"(hh));
      }
    }
  }

  // plain coalesced stores: per instr 4 rows x 16 consecutive floats = 4x64B segments
  const int hbase = (w << 4) + c;
#pragma unroll
  for (int as = 0; as < 4; ++as) {
    const int ebase = eblk + as * 16 + (g << 2);
    m[((ebase + 0) << 6) + hbase] = accA[as][0];
    m[((ebase + 1) << 6) + hbase] = accA[as][1];
    m[((ebase + 2) << 6) + hbase] = accB[as][0];
    m[((ebase + 3) << 6) + hbase] = accB[as][1];
  }
}

// ---- final: gather-mean per dst (CSR) fused with out = relu(concat@Wn + bn) ----
// Block: 4 waves x 2 rows each = 8 rows; grid 1024. Wn in LDS (32 KB); 2-deep gather ILP.
__global__ __launch_bounds__(256) void final5_kernel(
    const float* __restrict__ nf, const float* __restrict__ m,
    const int* __restrict__ off, const int* __restrict__ eid,
    const float* __restrict__ Wn, const float* __restrict__ bn,
    float* __restrict__ out) {
  __shared__ float wn_s[128 * 64];   // 32 KB
  __shared__ float hn_s[8 * 64];     // 2 KB
  const int t = threadIdx.x;
#pragma unroll
  for (int i = 0; i < 8; ++i)
    ((f32x4*)wn_s)[i * 256 + t] = ((const f32x4*)Wn)[i * 256 + t];

  const int w = t >> 6, h = t & 63;
  const int row0 = blockIdx.x * 8 + w * 2;

#pragma unroll
  for (int i = 0; i < 2; ++i) {
    const int d = row0 + i;
    const int lo = off[d], hi = off[d + 1];
    float a0 = 0.f, a1 = 0.f;
    int j = lo;
    for (; j + 2 <= hi; j += 2) {
      const int e0 = eid[j], e1 = eid[j + 1];
      a0 += m[(e0 << 6) + h];
      a1 += m[(e1 << 6) + h];
    }
    if (j < hi) a0 += m[(eid[j] << 6) + h];
    const float a = a0 + a1;
    hn_s[(w * 2 + i) * 64 + h] = (hi > lo) ? a * (1.f / (float)(hi - lo)) : 0.f;
  }
  __syncthreads();

  const float bv = bn[h];
  float acc[2] = {bv, bv};
#pragma unroll 4
  for (int k = 0; k < 64; ++k) {
    const float wv = wn_s[k * 64 + h];
#pragma unroll
    for (int i = 0; i < 2; ++i)
      acc[i] = fmaf(nf[(row0 + i) * 64 + k], wv, acc[i]);
  }
#pragma unroll 4
  for (int k = 0; k < 64; ++k) {
    const float wv = wn_s[(64 + k) * 64 + h];
#pragma unroll
    for (int i = 0; i < 2; ++i)
      acc[i] = fmaf(hn_s[(w * 2 + i) * 64 + k], wv, acc[i]);
  }
#pragma unroll
  for (int i = 0; i < 2; ++i)
    out[(row0 + i) * 64 + h] = fmaxf(acc[i], 0.f);
}

// ================= atomic fallback (R3, proven) =================

__global__ __launch_bounds__(256, 4) void edge_kernel(
    const float* __restrict__ nf, const float* __restrict__ ef,
    const int* __restrict__ src, const int* __restrict__ dst,
    const __bf16* __restrict__ Wp, const float* __restrict__ bp,
    float* __restrict__ msum, float* __restrict__ cnt_g) {
  __shared__ __bf16 hs[64 * EPW];
  const int t = threadIdx.x;
  const int eblk = blockIdx.x << 6;
  {
    const int el = t & 63, q = t >> 6;
    const int srow = src[eblk + el];
    const f32x4* nfr = (const f32x4*)(nf + (srow << 6) + (q << 4));
#pragma unroll
    for (int i = 0; i < 4; ++i) {
      f32x4 v = nfr[i];
      const int dbase = (q << 4) + i * 4;
      hs[(dbase + 0) * EPW + el] = (__bf16)v[0];
      hs[(dbase + 1) * EPW + el] = (__bf16)v[1];
      hs[(dbase + 2) * EPW + el] = (__bf16)v[2];
      hs[(dbase + 3) * EPW + el] = (__bf16)v[3];
    }
  }
  const int w = t >> 6, l = t & 63, c = l & 15, g = l >> 4;
  bf16x8 afr[4];
#pragma unroll
  for (int as = 0; as < 4; ++as) {
    const int e = eblk + as * 16 + c;
    const f32x4* p = (const f32x4*)(ef + (e << 5) + (g << 3));
    f32x4 v0 = p[0], v1 = p[1];
    bf16x8 a;
    a[0] = (__bf16)v0[0]; a[1] = (__bf16)v0[1]; a[2] = (__bf16)v0[2]; a[3] = (__bf16)v0[3];
    a[4] = (__bf16)v1[0]; a[5] = (__bf16)v1[1]; a[6] = (__bf16)v1[2]; a[7] = (__bf16)v1[3];
    afr[as] = a;
  }
  __syncthreads();
  f32x4 acc[4];
#pragma unroll
  for (int i = 0; i < 4; ++i) { acc[i][0]=0.f; acc[i][1]=0.f; acc[i][2]=0.f; acc[i][3]=0.f; }
  const bf16x8* WpV = (const bf16x8*)Wp;
  const f32x4 zero = {0.f, 0.f, 0.f, 0.f};
#pragma unroll 4
  for (int d0 = 0; d0 < 64; ++d0) {
    const int T = d0 * 4 + w;
    const bf16x8 bfr = WpV[T * 64 + l];
    const float bv = bp[T * 16 + c];
    const f32x4 cb = {bv, bv, bv, bv};
#pragma unroll
    for (int as = 0; as < 4; ++as) {
      const bf16x4 hv = *(const bf16x4*)&hs[d0 * EPW + as * 16 + (g << 2)];
      const f32x4 hvf = {(float)hv[0], (float)hv[1], (float)hv[2], (float)hv[3]};
      f32x4 tmp = __builtin_amdgcn_mfma_f32_16x16x32_bf16(afr[as], bfr, cb, 0, 0, 0);
      tmp = __builtin_elementwise_max(tmp, zero);
      acc[as] = tmp * hvf + acc[as];
    }
  }
#pragma unroll
  for (int as = 0; as < 4; ++as)
#pragma unroll
    for (int r = 0; r < 4; ++r) {
      const int e = eblk + as * 16 + (g << 2) + r;
      const int dd = dst[e];
      unsafeAtomicAdd(msum + (dd << 6) + (w << 4) + c, acc[as][r]);
      if (w == 0 && c == 0) unsafeAtomicAdd(cnt_g + dd, 1.0f);
    }
}

__global__ __launch_bounds__(256) void final_kernel(
    const float* __restrict__ nf, const float* __restrict__ msum,
    const float* __restrict__ cnt, const float* __restrict__ Wn,
    const float* __restrict__ bn, float* __restrict__ out) {
  __shared__ float wn_s[128 * 64];
  const int t = threadIdx.x;
#pragma unroll
  for (int i = 0; i < 8; ++i)
    ((f32x4*)wn_s)[i * 256 + t] = ((const f32x4*)Wn)[i * 256 + t];
  __syncthreads();
  const int w = t >> 6, h = t & 63;
  const int row0 = blockIdx.x * 16 + w * 4;
  const float bv = bn[h];
  float acc[4] = {bv, bv, bv, bv};
  float s[4];
#pragma unroll
  for (int i = 0; i < 4; ++i) {
    const float cv = cnt[row0 + i];
    s[i] = cv > 0.f ? 1.f / cv : 0.f;
  }
#pragma unroll 4
  for (int k = 0; k < 64; ++k) {
    const float wv = wn_s[k * 64 + h];
#pragma unroll
    for (int i = 0; i < 4; ++i) acc[i] = fmaf(nf[(row0 + i) * 64 + k], wv, acc[i]);
  }
#pragma unroll 4
  for (int k = 0; k < 64; ++k) {
    const float wv = wn_s[(64 + k) * 64 + h];
#pragma unroll
    for (int i = 0; i < 4; ++i) acc[i] = fmaf(msum[(row0 + i) * 64 + k] * s[i], wv, acc[i]);
  }
#pragma unroll
  for (int i = 0; i < 4; ++i) out[(row0 + i) * 64 + h] = fmaxf(acc[i], 0.f);
}

// ================= launcher =================

extern "C" void kernel_launch(void* const* d_in, const int* in_sizes, int n_in,
                              void* d_out, int out_size, void* d_ws, size_t ws_size,
                              hipStream_t stream) {
  const float* nf  = (const float*)d_in[0];
  const float* ef  = (const float*)d_in[1];
  const int*   src = (const int*)d_in[2];
  const int*   dst = (const int*)d_in[3];
  const float* We  = (const float*)d_in[4];
  const float* be  = (const float*)d_in[5];
  const float* Wn  = (const float*)d_in[6];
  const float* bn  = (const float*)d_in[7];
  float* out = (float*)d_out;
  char* ws = (char*)d_ws;

  const size_t MB = 16777216;  // m buffer bytes (E*64*4)
  const size_t T_OFF    = MB;
  const size_t T_CURSOR = T_OFF + 36864;
  const size_t T_CNTI   = T_CURSOR + 32768;
  const size_t T_EID    = T_CNTI + 32768;
  const size_t T_WP     = T_EID + 262144;
  const size_t T_BP     = T_WP + 262144;
  const size_t NEED     = T_BP + 16384;      // ~17.4 MB

  if (ws_size >= NEED) {
    float*  m      = (float*)ws;
    int*    off    = (int*)(ws + T_OFF);
    int*    cursor = (int*)(ws + T_CURSOR);
    int*    cnt_i  = (int*)(ws + T_CNTI);
    int*    eid    = (int*)(ws + T_EID);
    __bf16* Wp     = (__bf16*)(ws + T_WP);
    float*  bp     = (float*)(ws + T_BP);

    hipMemsetAsync(cnt_i, 0, 32768, stream);
    prep_kernel<<<64, 256, 0, stream>>>(We, be, Wp, bp);
    edge5_kernel<<<E_TOT / 64, 256, 0, stream>>>(nf, ef, src, dst, Wp, bp, m, cnt_i);
    scan_kernel<<<1, 256, 0, stream>>>(cnt_i, off, cursor);
    fill_kernel<<<E_TOT / 256, 256, 0, stream>>>(dst, cursor, eid);
    final5_kernel<<<NDST / 8, 256, 0, stream>>>(nf, m, off, eid, Wn, bn, out);
  } else {
    // atomic fallback
    float* msum = (float*)ws;
    float* cnt  = (float*)(ws + 2097152);
    const size_t need = 2097152 + 32768 + 262144 + 16384;
    __bf16* Wp;
    float*  bp;
    if (ws_size >= need) {
      Wp = (__bf16*)(ws + 2097152 + 32768);
      bp = (float*)(ws + 2097152 + 32768 + 262144);
    } else {
      Wp = (__bf16*)d_out;
      bp = (float*)((char*)d_out + 262144);
    }
    hipMemsetAsync(msum, 0, 2097152 + 32768, stream);
    prep_kernel<<<64, 256, 0, stream>>>(We, be, Wp, bp);
    edge_kernel<<<E_TOT / 64, 256, 0, stream>>>(nf, ef, src, dst, Wp, bp, msum, cnt);
    final_kernel<<<NDST / 16, 256, 0, stream>>>(nf, msum, cnt, Wn, bn, out);
  }
}